// Round 1
// baseline (2333.734 us; speedup 1.0000x reference)
//
#include <hip/hip_runtime.h>

#define N_TOK 65536
#define DIM   256
#define K_CB  4096

#define BM    64    // tokens per block
#define BKC   128   // codes per outer chunk
#define BSTR  (BKC + 8)  // Bs row stride (floats)
#define DCH   16    // d-depth per LDS stage
#define MARGIN 2e-4f

// ---------------------------------------------------------------- b2 = ||c_k||^2
__global__ void b2_kernel(const float* __restrict__ cb, float* __restrict__ b2) {
    int gid = blockIdx.x * blockDim.x + threadIdx.x;
    int w = gid >> 6, lane = gid & 63;
    if (w >= K_CB) return;
    float4 v = reinterpret_cast<const float4*>(cb + (size_t)w * DIM)[lane];
    float s = (v.x * v.x + v.y * v.y) + (v.z * v.z + v.w * v.w);
#pragma unroll
    for (int off = 1; off < 64; off <<= 1) s += __shfl_xor(s, off, 64);
    if (lane == 0) b2[w] = s;
}

// ---------------------------------------------------------------- fused dist+argmin
// score[n][k] = b2[k] - 2 * dot(x[n], cb[k])  (a2 shifts all k equally -> dropped)
__global__ __launch_bounds__(256, 2) void argmin_kernel(
    const float* __restrict__ x, const float* __restrict__ cb,
    const float* __restrict__ b2, int* __restrict__ bestIdx,
    int* __restrict__ flagCnt, int* __restrict__ flagList)
{
    __shared__ float As[DIM][BM];        // 64 KB, [d][token]
    __shared__ float Bs[DCH][BSTR];      // ~8.7 KB, [d][code'], col-swizzled

    const int tid = threadIdx.x;
    const int tx = tid & 15, ty = tid >> 4;
    const int n0 = blockIdx.x * BM;
    const int w = tx & 4;                // column XOR swizzle for this thread

    // ---- stage x tile transposed: As[d][r] = x[n0+r][d]
    {
        const int r  = tid >> 2;          // 0..63
        const int qb = (tid & 3) << 4;    // float4 base 0,16,32,48
        const float4* xrow = reinterpret_cast<const float4*>(x + (size_t)(n0 + r) * DIM);
#pragma unroll
        for (int i = 0; i < 16; ++i) {
            float4 v = xrow[qb + i];
            int d = (qb + i) << 2;
            As[d + 0][r] = v.x; As[d + 1][r] = v.y;
            As[d + 2][r] = v.z; As[d + 3][r] = v.w;
        }
    }

    float b1d[4], b2dv[4]; int b1i[4];
#pragma unroll
    for (int i = 0; i < 4; ++i) { b1d[i] = 3.0e38f; b2dv[i] = 3.0e38f; b1i[i] = 0; }

    for (int kc = 0; kc < K_CB; kc += BKC) {
        float acc[4][8];
#pragma unroll
        for (int i = 0; i < 4; ++i)
#pragma unroll
            for (int j = 0; j < 8; ++j) acc[i][j] = 0.f;

        for (int dc = 0; dc < DIM; dc += DCH) {
            __syncthreads();
            // stage Bs[dd][c ^ swz(c)] = cb[kc+c][dc+dd]
#pragma unroll
            for (int it = 0; it < 2; ++it) {
                int l  = it * 256 + tid;          // 0..511
                int c  = l >> 2;                  // 0..127
                int f4 = l & 3;                   // 0..3
                float4 v = *reinterpret_cast<const float4*>(
                    cb + (size_t)(kc + c) * DIM + dc + (f4 << 2));
                int cs = c ^ ((c >> 3) & 4);      // xor bit5(c) into bit2
                int dd = f4 << 2;
                Bs[dd + 0][cs] = v.x; Bs[dd + 1][cs] = v.y;
                Bs[dd + 2][cs] = v.z; Bs[dd + 3][cs] = v.w;
            }
            __syncthreads();
#pragma unroll
            for (int dd = 0; dd < DCH; ++dd) {
                const int d = dc + dd;            // ascending-d single FMA chain
                float4 a  = *reinterpret_cast<const float4*>(&As[d][ty << 2]);
                float4 q0 = *reinterpret_cast<const float4*>(&Bs[dd][tx << 3]);
                float4 q1 = *reinterpret_cast<const float4*>(&Bs[dd][(tx << 3) + 4]);
                float av[4] = {a.x, a.y, a.z, a.w};
                float bv[8] = {q0.x, q0.y, q0.z, q0.w, q1.x, q1.y, q1.z, q1.w};
#pragma unroll
                for (int i = 0; i < 4; ++i)
#pragma unroll
                    for (int j = 0; j < 8; ++j)
                        acc[i][j] = fmaf(av[i], bv[j], acc[i][j]);
            }
        }

        // epilogue: dist + running top-2 (acc[i][j] holds col kc + 8*tx + (j^w))
        float4 p0 = *reinterpret_cast<const float4*>(b2 + kc + (tx << 3));
        float4 p1 = *reinterpret_cast<const float4*>(b2 + kc + (tx << 3) + 4);
        float4 lo = w ? p1 : p0;
        float4 hi = w ? p0 : p1;
        float b2s[8] = {lo.x, lo.y, lo.z, lo.w, hi.x, hi.y, hi.z, hi.w};
#pragma unroll
        for (int i = 0; i < 4; ++i) {
#pragma unroll
            for (int j = 0; j < 8; ++j) {
                float dist = fmaf(-2.f, acc[i][j], b2s[j]);
                int k = kc + (tx << 3) + (j ^ w);
                bool better = (dist < b1d[i]) || (dist == b1d[i] && k < b1i[i]);
                if (better) { b2dv[i] = b1d[i]; b1d[i] = dist; b1i[i] = k; }
                else         b2dv[i] = fminf(b2dv[i], dist);
            }
        }
    }

    // ---- block reduce across the 16 tx-threads per row (alias As, loop is done)
    __syncthreads();
    char* base = reinterpret_cast<char*>(&As[0][0]);
    float* rb1d = reinterpret_cast<float*>(base);            // [64][16]
    int*   rb1i = reinterpret_cast<int*>(base + 4096);
    float* rb2d = reinterpret_cast<float*>(base + 8192);
#pragma unroll
    for (int i = 0; i < 4; ++i) {
        int row = (ty << 2) + i;
        rb1d[row * 16 + tx] = b1d[i];
        rb1i[row * 16 + tx] = b1i[i];
        rb2d[row * 16 + tx] = b2dv[i];
    }
    __syncthreads();
    if (tid < BM) {
        int row = tid;
        float s1 = 3.0e38f, s2 = 3.0e38f; int si = 0;
#pragma unroll
        for (int t = 0; t < 16; ++t) {
            float d1 = rb1d[row * 16 + t]; int i1 = rb1i[row * 16 + t];
            float d2 = rb2d[row * 16 + t];
            if (d1 < s1 || (d1 == s1 && i1 < si)) { s2 = fminf(s1, d2); s1 = d1; si = i1; }
            else                                   s2 = fminf(s2, d1);
        }
        int n = n0 + row;
        bestIdx[n] = si;
        if (s2 - s1 < MARGIN) {           // near-tie -> exact fp64 re-resolve
            int pos = atomicAdd(flagCnt, 1);
            flagList[pos] = n;
        }
    }
}

// ---------------------------------------------------------------- fp64 exact refine
__global__ void refine_kernel(const float* __restrict__ x, const float* __restrict__ cb,
                              const int* __restrict__ flagCnt, const int* __restrict__ flagList,
                              int* __restrict__ bestIdx)
{
    __shared__ float  xr[DIM];
    __shared__ double rd[256];
    __shared__ int    ri[256];
    const int tid = threadIdx.x;
    const int cnt = *flagCnt;
    for (int f = blockIdx.x; f < cnt; f += gridDim.x) {
        const int n = flagList[f];
        __syncthreads();
        if (tid < DIM / 4) {
            float4 v = reinterpret_cast<const float4*>(x + (size_t)n * DIM)[tid];
            xr[tid * 4 + 0] = v.x; xr[tid * 4 + 1] = v.y;
            xr[tid * 4 + 2] = v.z; xr[tid * 4 + 3] = v.w;
        }
        __syncthreads();
        double best = 1e300; int bi = K_CB;
        for (int k = tid; k < K_CB; k += 256) {
            const float* crow = cb + (size_t)k * DIM;
            double dot = 0.0, nb = 0.0;
            for (int d = 0; d < DIM; d += 4) {
                float4 cv = *reinterpret_cast<const float4*>(crow + d);
                dot += (double)cv.x * xr[d]     + (double)cv.y * xr[d + 1]
                     + (double)cv.z * xr[d + 2] + (double)cv.w * xr[d + 3];
                nb  += (double)cv.x * cv.x + (double)cv.y * cv.y
                     + (double)cv.z * cv.z + (double)cv.w * cv.w;
            }
            double dist = nb - 2.0 * dot;
            if (dist < best || (dist == best && k < bi)) { best = dist; bi = k; }
        }
        rd[tid] = best; ri[tid] = bi;
        __syncthreads();
        for (int s = 128; s > 0; s >>= 1) {
            if (tid < s) {
                double od = rd[tid + s]; int oi = ri[tid + s];
                if (od < rd[tid] || (od == rd[tid] && oi < ri[tid])) { rd[tid] = od; ri[tid] = oi; }
            }
            __syncthreads();
        }
        if (tid == 0) bestIdx[n] = ri[0];
        __syncthreads();
    }
}

// ---------------------------------------------------------------- gather out rows
__global__ void gather_kernel(const float* __restrict__ cb, const int* __restrict__ bestIdx,
                              float* __restrict__ out)
{
    int t = blockIdx.x * 256 + threadIdx.x;   // 0 .. N_TOK*64-1 (float4 units)
    int n = t >> 6, f4 = t & 63;
    int k = bestIdx[n];
    reinterpret_cast<float4*>(out)[t] =
        reinterpret_cast<const float4*>(cb + (size_t)k * DIM)[f4];
}

extern "C" void kernel_launch(void* const* d_in, const int* in_sizes, int n_in,
                              void* d_out, int out_size, void* d_ws, size_t ws_size,
                              hipStream_t stream)
{
    const float* x  = (const float*)d_in[0];
    const float* cb = (const float*)d_in[1];
    float* out = (float*)d_out;

    char* ws = (char*)d_ws;
    float* b2       = (float*)ws;                       // 4096 floats
    int*   bestIdx  = (int*)(ws + 16384);               // 65536 ints
    int*   flagCnt  = (int*)(ws + 16384 + 262144);      // 1 int
    int*   flagList = flagCnt + 4;                      // 65536 ints

    hipMemsetAsync(flagCnt, 0, sizeof(int), stream);
    b2_kernel<<<dim3(1024), dim3(256), 0, stream>>>(cb, b2);
    argmin_kernel<<<dim3(N_TOK / BM), dim3(256), 0, stream>>>(x, cb, b2, bestIdx, flagCnt, flagList);
    refine_kernel<<<dim3(128), dim3(256), 0, stream>>>(x, cb, flagCnt, flagList, bestIdx);
    gather_kernel<<<dim3(N_TOK * 64 / 256), dim3(256), 0, stream>>>(cb, bestIdx, out);
}